// Round 2
// baseline (879.315 us; speedup 1.0000x reference)
//
#include <hip/hip_runtime.h>
#include <hip/hip_bf16.h>

typedef __bf16 bf16x8 __attribute__((ext_vector_type(8)));
typedef float floatx4 __attribute__((ext_vector_type(4)));

__device__ __forceinline__ ushort f2bf(float f) {
  union { float f; unsigned u; } v; v.f = f;
  unsigned r = ((v.u >> 16) & 1u) + 0x7FFFu;
  return (ushort)((v.u + r) >> 16);
}
__device__ __forceinline__ float bf2f(ushort u) {
  union { unsigned u; float f; } v; v.u = ((unsigned)u) << 16;
  return v.f;
}

// async global->LDS, 16B per lane. LDS dest must be linear in lane order (G21):
// swizzling is done by permuting the per-lane GLOBAL source address.
__device__ __forceinline__ void cp16(const void* g, void* l) {
  __builtin_amdgcn_global_load_lds((const __attribute__((address_space(1))) unsigned int*)g,
                                   (__attribute__((address_space(3))) unsigned int*)l,
                                   16, 0, 0);
}

// ---------------- fp32 -> bf16 cast (4 elems/thread) ----------------
__global__ __launch_bounds__(256) void cast_kernel(const float* __restrict__ in,
                                                   ushort* __restrict__ out) {
  size_t idx = (size_t)blockIdx.x * 256 + threadIdx.x;
  float4 v = ((const float4*)in)[idx];
  ushort4 o;
  o.x = f2bf(v.x); o.y = f2bf(v.y); o.z = f2bf(v.z); o.w = f2bf(v.w);
  ((ushort4*)out)[idx] = o;
}

// ---------------- GEMM: C[M,N] = A[M,K] * B[N,K]^T (+bias) ----------------
// M=2048, N=4096, K=4096. 128x128 tile, BK=32, 4 waves (2x2), 16x16x32 bf16 MFMA.
// EPI 0: bf16 out in [h][s][128] layout (h = col>>7).  EPI 1: fp32 out [M][N].
template <int EPI>
__global__ __launch_bounds__(256) void gemm_bt(const ushort* __restrict__ A,
                                               const ushort* __restrict__ B,
                                               const float* __restrict__ bias,
                                               void* __restrict__ outp) {
  constexpr int K = 4096, N = 4096;
  __shared__ ushort As[2][128 * 32];
  __shared__ ushort Bs[2][128 * 32];

  unsigned bid = blockIdx.x;
  unsigned swz = (bid & 7u) * (gridDim.x >> 3) + (bid >> 3);  // bijective: 512 % 8 == 0
  int tm = swz >> 5;   // 16 m-tiles
  int tn = swz & 31;   // 32 n-tiles (consecutive swz share the A panel -> L2)
  int m0 = tm << 7, n0 = tn << 7;

  int t = threadIdx.x;
  int l = t & 63;
  int w = t >> 6;
  int wm = (w >> 1) << 6;
  int wn = (w & 1) << 6;

  floatx4 zero4 = {0.f, 0.f, 0.f, 0.f};
  floatx4 acc[4][4];
#pragma unroll
  for (int i = 0; i < 4; ++i)
#pragma unroll
    for (int j = 0; j < 4; ++j) acc[i][j] = zero4;

  int rr = t >> 2;   // row within 64-row staging group
  int sp = t & 3;    // physical 16B slot within 64B row

  auto stage = [&](int buf, int kt) {
    int k0 = kt << 5;
#pragma unroll
    for (int iss = 0; iss < 2; ++iss) {
      int r = iss * 64 + rr;
      int sl = sp ^ (r & 3);  // inverse-swizzled source slot
      cp16(A + (size_t)(m0 + r) * K + k0 + sl * 8, &As[buf][(iss * 256 + t) * 8]);
      cp16(B + (size_t)(n0 + r) * K + k0 + sl * 8, &Bs[buf][(iss * 256 + t) * 8]);
    }
  };

  stage(0, 0);
  __syncthreads();
  int buf = 0;
  for (int kt = 0; kt < K / 32; ++kt) {
    if (kt + 1 < K / 32) stage(buf ^ 1, kt + 1);
    bf16x8 af[4], bfr[4];
#pragma unroll
    for (int i = 0; i < 4; ++i) {
      int ra = wm + i * 16 + (l & 15);
      af[i] = *(const bf16x8*)&As[buf][ra * 32 + (((l >> 4) ^ (ra & 3)) * 8)];
      int rb = wn + i * 16 + (l & 15);
      bfr[i] = *(const bf16x8*)&Bs[buf][rb * 32 + (((l >> 4) ^ (rb & 3)) * 8)];
    }
#pragma unroll
    for (int i = 0; i < 4; ++i)
#pragma unroll
      for (int j = 0; j < 4; ++j)
        acc[i][j] = __builtin_amdgcn_mfma_f32_16x16x32_bf16(af[i], bfr[j], acc[i][j], 0, 0, 0);
    __syncthreads();
    buf ^= 1;
  }

#pragma unroll
  for (int i = 0; i < 4; ++i)
#pragma unroll
    for (int j = 0; j < 4; ++j)
#pragma unroll
      for (int r = 0; r < 4; ++r) {
        int row = m0 + wm + i * 16 + ((l >> 4) << 2) + r;  // C/D: row=(l>>4)*4+reg
        int col = n0 + wn + j * 16 + (l & 15);             //      col=l&15
        float v = acc[i][j][r] + bias[col];
        if constexpr (EPI == 0) {
          ((ushort*)outp)[((size_t)(col >> 7) * 2048 + row) * 128 + (col & 127)] = f2bf(v);
        } else {
          ((float*)outp)[(size_t)row * N + col] = v;
        }
      }
}

// ---------------- RoPE, in-place on [32][2048][128] bf16 (Q or K) ----------------
__global__ __launch_bounds__(256) void rope_kernel(ushort* __restrict__ Q,
                                                   ushort* __restrict__ K) {
  unsigned idx = blockIdx.x * 256 + threadIdx.x;  // [0, 2^20)
  ushort* p = blockIdx.y ? K : Q;
  int i4 = idx & 15;
  int s = (idx >> 4) & 2047;
  size_t base = ((size_t)(idx >> 15) * 2048 + s) * 128 + (size_t)i4 * 8;
  ushort v[8];
  *(uint4*)v = *(const uint4*)(p + base);
  const float C = 0.14391156516f;  // ln(10000)/64
#pragma unroll
  for (int j = 0; j < 4; ++j) {
    int i = i4 * 4 + j;
    float theta = expf(-C * (float)i);
    float ang = (float)s * theta;
    float cs = cosf(ang), sn = sinf(ang);
    float e = bf2f(v[2 * j]), o = bf2f(v[2 * j + 1]);
    v[2 * j]     = f2bf(e * cs - o * sn);
    v[2 * j + 1] = f2bf(e * sn + o * cs);
  }
  *(uint4*)(p + base) = *(uint4*)v;
}

// ---------------- V[h][s][128] -> Vt[h][128][2048] ----------------
__global__ __launch_bounds__(256) void transpose_v(const ushort* __restrict__ V,
                                                   ushort* __restrict__ Vt) {
  __shared__ ushort tile[64][72];
  int st = blockIdx.x, dt = blockIdx.y, h = blockIdx.z;
  int t = threadIdx.x;
  int rl = t >> 2, c16 = (t & 3) * 16;
  const ushort* src = V + ((size_t)(h * 2048 + st * 64 + rl)) * 128 + dt * 64 + c16;
  *(uint4*)&tile[rl][c16] = *(const uint4*)src;
  *(uint4*)&tile[rl][c16 + 8] = *(const uint4*)(src + 8);
  __syncthreads();
  int d = t >> 2, s16 = (t & 3) * 16;
  __align__(16) ushort tmp[16];
#pragma unroll
  for (int j = 0; j < 16; ++j) tmp[j] = tile[s16 + j][d];
  ushort* dst = Vt + ((size_t)(h * 128 + dt * 64 + d)) * 2048 + st * 64 + s16;
  *(uint4*)dst = *(uint4*)tmp;
  *(uint4*)(dst + 8) = *(uint4*)(tmp + 8);
}

// ---------------- causal flash attention ----------------
// block = (qt, h); 4 waves x 16 q-rows; K-tile = 64. Q in regs; K,Vt staged via
// global_load_lds with XOR-swizzle (breaks the 16-way [.][128] bank conflict).
__global__ __launch_bounds__(256) void attn_kernel(const ushort* __restrict__ Qb,
                                                   const ushort* __restrict__ Kb,
                                                   const ushort* __restrict__ Vt,
                                                   ushort* __restrict__ aO) {
  __shared__ ushort Ks[64 * 128];
  __shared__ ushort Vs[128 * 64];
  __shared__ ushort Ps[4][16 * 64];

  int qt = blockIdx.x;
  int h = blockIdx.y;
  int t = threadIdx.x;
  int l = t & 63;
  int w = t >> 6;

  bf16x8 qf[4];
  {
    int qrow = qt * 64 + w * 16 + (l & 15);
    const ushort* qp = Qb + ((size_t)(h * 2048 + qrow)) * 128 + ((l >> 4) * 8);
#pragma unroll
    for (int ks = 0; ks < 4; ++ks) qf[ks] = *(const bf16x8*)(qp + ks * 32);
  }

  float m[4], lsum[4];
#pragma unroll
  for (int r = 0; r < 4; ++r) { m[r] = -1e30f; lsum[r] = 0.f; }
  floatx4 zero4 = {0.f, 0.f, 0.f, 0.f};
  floatx4 oacc[8];
#pragma unroll
  for (int i = 0; i < 8; ++i) oacc[i] = zero4;

  const float scale = 0.08838834764831845f;  // 1/sqrt(128)

  for (int kt = 0; kt <= qt; ++kt) {
    {
      int rk = t >> 4, sk = t & 15;
      int rv = t >> 3, sv = t & 7;
#pragma unroll
      for (int iss = 0; iss < 4; ++iss) {
        int row = iss * 16 + rk;
        int sl = sk ^ (row & 7);
        cp16(Kb + ((size_t)(h * 2048 + kt * 64 + row)) * 128 + sl * 8,
             &Ks[(iss * 256 + t) * 8]);
        int rowv = iss * 32 + rv;
        int slv = sv ^ (rowv & 7);
        cp16(Vt + ((size_t)(h * 128 + rowv)) * 2048 + kt * 64 + slv * 8,
             &Vs[(iss * 256 + t) * 8]);
      }
    }
    __syncthreads();

    // QK^T: S[16q x 64k]
    floatx4 sacc[4];
#pragma unroll
    for (int nt = 0; nt < 4; ++nt) sacc[nt] = zero4;
#pragma unroll
    for (int nt = 0; nt < 4; ++nt) {
      int row = nt * 16 + (l & 15);
#pragma unroll
      for (int ks = 0; ks < 4; ++ks) {
        bf16x8 kf = *(const bf16x8*)&Ks[row * 128 + (((ks * 4 + (l >> 4)) ^ (row & 7)) * 8)];
        sacc[nt] = __builtin_amdgcn_mfma_f32_16x16x32_bf16(qf[ks], kf, sacc[nt], 0, 0, 0);
      }
    }

    float sv_[4][4];
    float mt[4] = {-1e30f, -1e30f, -1e30f, -1e30f};
#pragma unroll
    for (int nt = 0; nt < 4; ++nt)
#pragma unroll
      for (int r = 0; r < 4; ++r) {
        float s = sacc[nt][r] * scale;
        if (kt == qt) {
          int kg = nt * 16 + (l & 15);
          int qg = w * 16 + ((l >> 4) << 2) + r;
          if (kg > qg) s = -1e30f;
        }
        sv_[nt][r] = s;
        mt[r] = fmaxf(mt[r], s);
      }
#pragma unroll
    for (int r = 0; r < 4; ++r)
#pragma unroll
      for (int msk = 1; msk < 16; msk <<= 1) mt[r] = fmaxf(mt[r], __shfl_xor(mt[r], msk, 64));

    float sf[4], mn[4];
#pragma unroll
    for (int r = 0; r < 4; ++r) {
      mn[r] = fmaxf(m[r], mt[r]);
      sf[r] = __expf(m[r] - mn[r]);
      m[r] = mn[r];
    }
#pragma unroll
    for (int i = 0; i < 8; ++i)
#pragma unroll
      for (int r = 0; r < 4; ++r) oacc[i][r] *= sf[r];

    float ps[4] = {0.f, 0.f, 0.f, 0.f};
    ushort* Pw = Ps[w];
#pragma unroll
    for (int nt = 0; nt < 4; ++nt)
#pragma unroll
      for (int r = 0; r < 4; ++r) {
        float p = __expf(sv_[nt][r] - mn[r]);
        ps[r] += p;
        int row = ((l >> 4) << 2) + r;
        int col = nt * 16 + (l & 15);
        int slot = (col >> 3) ^ (row & 7);
        Pw[row * 64 + slot * 8 + (col & 7)] = f2bf(p);
      }
#pragma unroll
    for (int r = 0; r < 4; ++r) {
#pragma unroll
      for (int msk = 1; msk < 16; msk <<= 1) ps[r] += __shfl_xor(ps[r], msk, 64);
      lsum[r] = lsum[r] * sf[r] + ps[r];
    }

    // PV: O[16q x 128d] += P[16x64] * Vt[128d][64k]^T
    bf16x8 pf[2];
#pragma unroll
    for (int ks = 0; ks < 2; ++ks) {
      int row = l & 15;
      pf[ks] = *(const bf16x8*)&Pw[row * 64 + (((ks * 4 + (l >> 4)) ^ (row & 7)) * 8)];
    }
#pragma unroll
    for (int nt = 0; nt < 8; ++nt) {
      int row = nt * 16 + (l & 15);
#pragma unroll
      for (int ks = 0; ks < 2; ++ks) {
        bf16x8 vf = *(const bf16x8*)&Vs[row * 64 + (((ks * 4 + (l >> 4)) ^ (row & 7)) * 8)];
        oacc[nt] = __builtin_amdgcn_mfma_f32_16x16x32_bf16(pf[ks], vf, oacc[nt], 0, 0, 0);
      }
    }
    __syncthreads();
  }

  float inv[4];
#pragma unroll
  for (int r = 0; r < 4; ++r) inv[r] = 1.0f / lsum[r];
#pragma unroll
  for (int nt = 0; nt < 8; ++nt)
#pragma unroll
    for (int r = 0; r < 4; ++r) {
      int row = qt * 64 + w * 16 + ((l >> 4) << 2) + r;
      int col = h * 128 + nt * 16 + (l & 15);
      aO[(size_t)row * 4096 + col] = f2bf(oacc[nt][r] * inv[r]);
    }
}

extern "C" void kernel_launch(void* const* d_in, const int* in_sizes, int n_in,
                              void* d_out, int out_size, void* d_ws, size_t ws_size,
                              hipStream_t stream) {
  const float* x  = (const float*)d_in[0];
  const float* Wq = (const float*)d_in[1];
  const float* bq = (const float*)d_in[2];
  const float* Wk = (const float*)d_in[3];
  const float* bk = (const float*)d_in[4];
  const float* Wv = (const float*)d_in[5];
  const float* bv = (const float*)d_in[6];
  const float* Wo = (const float*)d_in[7];
  const float* bo = (const float*)d_in[8];
  float* out = (float*)d_out;

  char* ws = (char*)d_ws;
  // layout (bytes), 96MB total with aliasing (stream order makes aliases safe):
  //   Wb 32MB | xb 16MB (later reused as Vt) | Qb 16MB | Kb 16MB | Vb 16MB (later aO)
  ushort* Wb = (ushort*)(ws);
  ushort* xb = (ushort*)(ws + 33554432);
  ushort* Qb = (ushort*)(ws + 50331648);
  ushort* Kb = (ushort*)(ws + 67108864);
  ushort* Vb = (ushort*)(ws + 83886080);
  ushort* Vt = xb;   // xb dead after the V-projection GEMM
  ushort* aO = Vb;   // Vb dead after transpose_v

  cast_kernel<<<8192, 256, 0, stream>>>(x, xb);
  cast_kernel<<<16384, 256, 0, stream>>>(Wq, Wb);
  gemm_bt<0><<<512, 256, 0, stream>>>(xb, Wb, bq, Qb);
  cast_kernel<<<16384, 256, 0, stream>>>(Wk, Wb);
  gemm_bt<0><<<512, 256, 0, stream>>>(xb, Wb, bk, Kb);
  cast_kernel<<<16384, 256, 0, stream>>>(Wv, Wb);
  gemm_bt<0><<<512, 256, 0, stream>>>(xb, Wb, bv, Vb);
  rope_kernel<<<dim3(4096, 2), 256, 0, stream>>>(Qb, Kb);
  transpose_v<<<dim3(32, 2, 32), 256, 0, stream>>>(Vb, Vt);
  attn_kernel<<<dim3(32, 32), 256, 0, stream>>>(Qb, Kb, Vt, aO);
  cast_kernel<<<16384, 256, 0, stream>>>(Wo, Wb);
  gemm_bt<1><<<512, 256, 0, stream>>>(aO, Wb, bo, out);
}

// Round 3
// 793.095 us; speedup vs baseline: 1.1087x; 1.1087x over previous
//
#include <hip/hip_runtime.h>
#include <hip/hip_bf16.h>

typedef __bf16 bf16x8 __attribute__((ext_vector_type(8)));
typedef float floatx4 __attribute__((ext_vector_type(4)));

__device__ __forceinline__ ushort f2bf(float f) {
  union { float f; unsigned u; } v; v.f = f;
  unsigned r = ((v.u >> 16) & 1u) + 0x7FFFu;
  return (ushort)((v.u + r) >> 16);
}
__device__ __forceinline__ float bf2f(ushort u) {
  union { unsigned u; float f; } v; v.u = ((unsigned)u) << 16;
  return v.f;
}

// async global->LDS, 16B per lane. LDS dest must be linear in lane order (G21):
// swizzling is done by permuting the per-lane GLOBAL source address.
__device__ __forceinline__ void cp16(const void* g, void* l) {
  __builtin_amdgcn_global_load_lds((const __attribute__((address_space(1))) unsigned int*)g,
                                   (__attribute__((address_space(3))) unsigned int*)l,
                                   16, 0, 0);
}

// ---------------- fp32 -> bf16 cast (4 elems/thread) ----------------
__global__ __launch_bounds__(256) void cast_kernel(const float* __restrict__ in,
                                                   ushort* __restrict__ out) {
  size_t idx = (size_t)blockIdx.x * 256 + threadIdx.x;
  float4 v = ((const float4*)in)[idx];
  ushort4 o;
  o.x = f2bf(v.x); o.y = f2bf(v.y); o.z = f2bf(v.z); o.w = f2bf(v.w);
  ((ushort4*)out)[idx] = o;
}

// ---------------- GEMM: C[M,N] = A[M,K] * B[N,K]^T (+bias) ----------------
// M=2048, N=4096, K=4096. 128x128 tile, BK=32, 4 waves (2x2), 16x16x32 bf16 MFMA.
// EPI 0: bf16 out in [h][s][128] layout (h = col>>7).  EPI 1: fp32 out [M][N].
template <int EPI>
__global__ __launch_bounds__(256) void gemm_bt(const ushort* __restrict__ A,
                                               const ushort* __restrict__ B,
                                               const float* __restrict__ bias,
                                               void* __restrict__ outp) {
  constexpr int K = 4096, N = 4096;
  __shared__ ushort As[2][128 * 32];
  __shared__ ushort Bs[2][128 * 32];

  unsigned bid = blockIdx.x;
  unsigned swz = (bid & 7u) * (gridDim.x >> 3) + (bid >> 3);  // bijective: 512 % 8 == 0
  int tm = swz >> 5;   // 16 m-tiles
  int tn = swz & 31;   // 32 n-tiles (consecutive swz share the A panel -> L2)
  int m0 = tm << 7, n0 = tn << 7;

  int t = threadIdx.x;
  int l = t & 63;
  int w = t >> 6;
  int wm = (w >> 1) << 6;
  int wn = (w & 1) << 6;

  floatx4 zero4 = {0.f, 0.f, 0.f, 0.f};
  floatx4 acc[4][4];
#pragma unroll
  for (int i = 0; i < 4; ++i)
#pragma unroll
    for (int j = 0; j < 4; ++j) acc[i][j] = zero4;

  int rr = t >> 2;   // row within 64-row staging group
  int sp = t & 3;    // physical 16B slot within 64B row

  auto stage = [&](int buf, int kt) {
    int k0 = kt << 5;
#pragma unroll
    for (int iss = 0; iss < 2; ++iss) {
      int r = iss * 64 + rr;
      int sl = sp ^ (r & 3);  // inverse-swizzled source slot
      cp16(A + (size_t)(m0 + r) * K + k0 + sl * 8, &As[buf][(iss * 256 + t) * 8]);
      cp16(B + (size_t)(n0 + r) * K + k0 + sl * 8, &Bs[buf][(iss * 256 + t) * 8]);
    }
  };

  stage(0, 0);
  __syncthreads();
  int buf = 0;
  for (int kt = 0; kt < K / 32; ++kt) {
    if (kt + 1 < K / 32) stage(buf ^ 1, kt + 1);
    bf16x8 af[4], bfr[4];
#pragma unroll
    for (int i = 0; i < 4; ++i) {
      int ra = wm + i * 16 + (l & 15);
      af[i] = *(const bf16x8*)&As[buf][ra * 32 + (((l >> 4) ^ (ra & 3)) * 8)];
      int rb = wn + i * 16 + (l & 15);
      bfr[i] = *(const bf16x8*)&Bs[buf][rb * 32 + (((l >> 4) ^ (rb & 3)) * 8)];
    }
#pragma unroll
    for (int i = 0; i < 4; ++i)
#pragma unroll
      for (int j = 0; j < 4; ++j)
        acc[i][j] = __builtin_amdgcn_mfma_f32_16x16x32_bf16(af[i], bfr[j], acc[i][j], 0, 0, 0);
    __syncthreads();
    buf ^= 1;
  }

#pragma unroll
  for (int i = 0; i < 4; ++i)
#pragma unroll
    for (int j = 0; j < 4; ++j)
#pragma unroll
      for (int r = 0; r < 4; ++r) {
        int row = m0 + wm + i * 16 + ((l >> 4) << 2) + r;  // C/D: row=(l>>4)*4+reg
        int col = n0 + wn + j * 16 + (l & 15);             //      col=l&15
        float v = acc[i][j][r] + bias[col];
        if constexpr (EPI == 0) {
          ((ushort*)outp)[((size_t)(col >> 7) * 2048 + row) * 128 + (col & 127)] = f2bf(v);
        } else {
          ((float*)outp)[(size_t)row * N + col] = v;
        }
      }
}

// ---------------- RoPE cos/sin table: tab[s][i] = {cos,sin}(s * theta_i) ----------------
__global__ __launch_bounds__(256) void rope_table(float2* __restrict__ tab) {
  int idx = blockIdx.x * 256 + threadIdx.x;  // 2048*64
  int i = idx & 63;
  int s = idx >> 6;
  const float C = 0.14391156516f;  // ln(10000)/64
  float theta = expf(-C * (float)i);
  float ang = (float)s * theta;
  tab[idx] = make_float2(cosf(ang), sinf(ang));
}

// ---------------- RoPE, in-place on [32][2048][128] bf16 (Q or K) ----------------
__global__ __launch_bounds__(256) void rope_kernel(ushort* __restrict__ Q,
                                                   ushort* __restrict__ K,
                                                   const float2* __restrict__ tab) {
  unsigned idx = blockIdx.x * 256 + threadIdx.x;  // [0, 2^20)
  ushort* p = blockIdx.y ? K : Q;
  int i4 = idx & 15;
  int s = (idx >> 4) & 2047;
  size_t base = ((size_t)(idx >> 15) * 2048 + s) * 128 + (size_t)i4 * 8;
  ushort v[8];
  *(uint4*)v = *(const uint4*)(p + base);
#pragma unroll
  for (int j = 0; j < 4; ++j) {
    float2 cs = tab[s * 64 + i4 * 4 + j];
    float e = bf2f(v[2 * j]), o = bf2f(v[2 * j + 1]);
    v[2 * j]     = f2bf(e * cs.x - o * cs.y);
    v[2 * j + 1] = f2bf(e * cs.y + o * cs.x);
  }
  *(uint4*)(p + base) = *(uint4*)v;
}

// ---------------- V[h][s][128] -> Vt[h][128][2048] ----------------
__global__ __launch_bounds__(256) void transpose_v(const ushort* __restrict__ V,
                                                   ushort* __restrict__ Vt) {
  __shared__ ushort tile[64][72];
  int st = blockIdx.x, dt = blockIdx.y, h = blockIdx.z;
  int t = threadIdx.x;
  int rl = t >> 2, c16 = (t & 3) * 16;
  const ushort* src = V + ((size_t)(h * 2048 + st * 64 + rl)) * 128 + dt * 64 + c16;
  *(uint4*)&tile[rl][c16] = *(const uint4*)src;
  *(uint4*)&tile[rl][c16 + 8] = *(const uint4*)(src + 8);
  __syncthreads();
  int d = t >> 2, s16 = (t & 3) * 16;
  __align__(16) ushort tmp[16];
#pragma unroll
  for (int j = 0; j < 16; ++j) tmp[j] = tile[s16 + j][d];
  ushort* dst = Vt + ((size_t)(h * 128 + dt * 64 + d)) * 2048 + st * 64 + s16;
  *(uint4*)dst = *(uint4*)tmp;
  *(uint4*)(dst + 8) = *(uint4*)(tmp + 8);
}

// ---------------- causal flash attention, balanced + double-buffered ----------------
// 256 blocks x 512 threads (8 waves x 16 q-rows = 128-row Q tile).
// Block handles q-tile PAIR (bi, 15-bi): exactly 34 K-tiles each -> perfect balance.
// All 8 blocks of a head land on one XCD (K/V L2-resident: 4 heads x 1MB per XCD).
// K/V double-buffered: stage(t+1) issued BEFORE compute(t), one barrier per tile.
__global__ __launch_bounds__(512) void attn_kernel(const ushort* __restrict__ Qb,
                                                   const ushort* __restrict__ Kb,
                                                   const ushort* __restrict__ Vt,
                                                   ushort* __restrict__ aO) {
  __shared__ ushort Ks[2][64 * 128];
  __shared__ ushort Vs[2][128 * 64];
  __shared__ ushort Ps[8][16 * 64];

  int bid = blockIdx.x;
  int xcd = bid & 7, slot = bid >> 3;  // consecutive bids round-robin XCDs (T1)
  int h = xcd * 4 + (slot >> 3);       // 4 heads per XCD
  int bi = slot & 7;                   // q-pair index: handles qt=bi then qt=15-bi

  int t = threadIdx.x;
  int l = t & 63;
  int w = t >> 6;

  const int n0t = 2 * bi + 2;  // K-tiles for qt=bi
  const int NT = 34;           // + 32-2*bi for qt=15-bi

  const float scale = 0.08838834764831845f;  // 1/sqrt(128)
  floatx4 zero4 = {0.f, 0.f, 0.f, 0.f};

  bf16x8 qf[4];
  float m[4], lsum[4];
  floatx4 oacc[8];

  auto loadQ = [&](int qt) {
    int qrow = qt * 128 + w * 16 + (l & 15);
    const ushort* qp = Qb + ((size_t)(h * 2048 + qrow)) * 128 + ((l >> 4) * 8);
#pragma unroll
    for (int ks = 0; ks < 4; ++ks) qf[ks] = *(const bf16x8*)(qp + ks * 32);
  };
  auto resetState = [&]() {
#pragma unroll
    for (int r = 0; r < 4; ++r) { m[r] = -1e30f; lsum[r] = 0.f; }
#pragma unroll
    for (int i = 0; i < 8; ++i) oacc[i] = zero4;
  };
  auto flushO = [&](int qt) {
    float inv[4];
#pragma unroll
    for (int r = 0; r < 4; ++r) inv[r] = 1.0f / lsum[r];
#pragma unroll
    for (int nt = 0; nt < 8; ++nt)
#pragma unroll
      for (int r = 0; r < 4; ++r) {
        int row = qt * 128 + w * 16 + ((l >> 4) << 2) + r;
        int col = h * 128 + nt * 16 + (l & 15);
        aO[(size_t)row * 4096 + col] = f2bf(oacc[nt][r] * inv[r]);
      }
  };
  // stage K-tile kt into buffer buf. 512 threads x 2 rounds x (K 16B + V 16B).
  auto stage = [&](int buf, int kt) {
#pragma unroll
    for (int iss = 0; iss < 2; ++iss) {
      int uu = iss * 512 + t;
      int rowk = uu >> 4, slk = (uu & 15) ^ (rowk & 7);
      cp16(Kb + ((size_t)(h * 2048 + kt * 64 + rowk)) * 128 + slk * 8,
           &Ks[buf][uu * 8]);
      int rowv = uu >> 3, slv = (uu & 7) ^ (rowv & 7);
      cp16(Vt + ((size_t)(h * 128 + rowv)) * 2048 + kt * 64 + slv * 8,
           &Vs[buf][uu * 8]);
    }
  };

  loadQ(bi);
  resetState();
  stage(0, 0);
  __syncthreads();

  int buf = 0;
  for (int it = 0; it < NT; ++it) {
    int qt = (it < n0t) ? bi : (15 - bi);
    int kt = (it < n0t) ? it : (it - n0t);

    // prefetch next tile into the other buffer (overlaps with compute below)
    if (it + 1 < NT) {
      int kn = (it + 1 < n0t) ? (it + 1) : (it + 1 - n0t);
      stage(buf ^ 1, kn);
    }

    // pass switch: flush q-tile bi, restart state for q-tile 15-bi
    if (it == n0t) {
      flushO(bi);
      resetState();
      loadQ(15 - bi);
    }

    int q0 = qt * 128;
    bool skipw = (kt * 64 > q0 + w * 16 + 15);  // tile fully masked for this wave
    if (!skipw) {
      // QK^T: S[16q x 64k]
      floatx4 sacc[4];
#pragma unroll
      for (int nt = 0; nt < 4; ++nt) sacc[nt] = zero4;
#pragma unroll
      for (int nt = 0; nt < 4; ++nt) {
        int row = nt * 16 + (l & 15);
#pragma unroll
        for (int ks = 0; ks < 4; ++ks) {
          bf16x8 kf = *(const bf16x8*)&Ks[buf][row * 128 + (((ks * 4 + (l >> 4)) ^ (row & 7)) * 8)];
          sacc[nt] = __builtin_amdgcn_mfma_f32_16x16x32_bf16(qf[ks], kf, sacc[nt], 0, 0, 0);
        }
      }

      bool diag = (kt * 64 + 63 > q0 + w * 16);  // masking touches this wave
      float sv_[4][4];
      float mt[4] = {-1e30f, -1e30f, -1e30f, -1e30f};
#pragma unroll
      for (int nt = 0; nt < 4; ++nt)
#pragma unroll
        for (int r = 0; r < 4; ++r) {
          float s = sacc[nt][r] * scale;
          if (diag) {
            int kg = kt * 64 + nt * 16 + (l & 15);
            int qg = q0 + w * 16 + ((l >> 4) << 2) + r;
            if (kg > qg) s = -1e30f;
          }
          sv_[nt][r] = s;
          mt[r] = fmaxf(mt[r], s);
        }
#pragma unroll
      for (int r = 0; r < 4; ++r)
#pragma unroll
        for (int msk = 1; msk < 16; msk <<= 1) mt[r] = fmaxf(mt[r], __shfl_xor(mt[r], msk, 64));

      float sf[4], mn[4];
#pragma unroll
      for (int r = 0; r < 4; ++r) {
        mn[r] = fmaxf(m[r], mt[r]);
        sf[r] = __expf(m[r] - mn[r]);
        m[r] = mn[r];
      }
#pragma unroll
      for (int i = 0; i < 8; ++i)
#pragma unroll
        for (int r = 0; r < 4; ++r) oacc[i][r] *= sf[r];

      float ps[4] = {0.f, 0.f, 0.f, 0.f};
      ushort* Pw = Ps[w];
#pragma unroll
      for (int nt = 0; nt < 4; ++nt)
#pragma unroll
        for (int r = 0; r < 4; ++r) {
          float p = __expf(sv_[nt][r] - mn[r]);
          ps[r] += p;
          int row = ((l >> 4) << 2) + r;
          int col = nt * 16 + (l & 15);
          int sl = (col >> 3) ^ (row & 7);
          Pw[row * 64 + sl * 8 + (col & 7)] = f2bf(p);
        }
#pragma unroll
      for (int r = 0; r < 4; ++r) {
#pragma unroll
        for (int msk = 1; msk < 16; msk <<= 1) ps[r] += __shfl_xor(ps[r], msk, 64);
        lsum[r] = lsum[r] * sf[r] + ps[r];
      }

      // PV: O[16q x 128d] += P[16x64] * Vt[128d][64k]^T
      bf16x8 pf[2];
#pragma unroll
      for (int ks = 0; ks < 2; ++ks) {
        int row = l & 15;
        pf[ks] = *(const bf16x8*)&Pw[row * 64 + (((ks * 4 + (l >> 4)) ^ (row & 7)) * 8)];
      }
#pragma unroll
      for (int nt = 0; nt < 8; ++nt) {
        int row = nt * 16 + (l & 15);
#pragma unroll
        for (int ks = 0; ks < 2; ++ks) {
          bf16x8 vf = *(const bf16x8*)&Vs[buf][row * 64 + (((ks * 4 + (l >> 4)) ^ (row & 7)) * 8)];
          oacc[nt] = __builtin_amdgcn_mfma_f32_16x16x32_bf16(pf[ks], vf, oacc[nt], 0, 0, 0);
        }
      }
    }
    __syncthreads();  // drains stage(buf^1) loads; all waves done reading buf
    buf ^= 1;
  }
  flushO(15 - bi);
}

extern "C" void kernel_launch(void* const* d_in, const int* in_sizes, int n_in,
                              void* d_out, int out_size, void* d_ws, size_t ws_size,
                              hipStream_t stream) {
  const float* x  = (const float*)d_in[0];
  const float* Wq = (const float*)d_in[1];
  const float* bq = (const float*)d_in[2];
  const float* Wk = (const float*)d_in[3];
  const float* bk = (const float*)d_in[4];
  const float* Wv = (const float*)d_in[5];
  const float* bv = (const float*)d_in[6];
  const float* Wo = (const float*)d_in[7];
  const float* bo = (const float*)d_in[8];
  float* out = (float*)d_out;

  char* ws = (char*)d_ws;
  // layout (bytes), 96MB total with aliasing (stream order makes aliases safe):
  //   Wb 32MB | xb 16MB (later reused as Vt) | Qb 16MB | Kb 16MB | Vb 16MB (later aO)
  ushort* Wb = (ushort*)(ws);
  ushort* xb = (ushort*)(ws + 33554432);
  ushort* Qb = (ushort*)(ws + 50331648);
  ushort* Kb = (ushort*)(ws + 67108864);
  ushort* Vb = (ushort*)(ws + 83886080);
  ushort* Vt = xb;            // xb dead after the V-projection GEMM
  ushort* aO = Vb;            // Vb dead after transpose_v
  float2* tab = (float2*)Wb;  // Wb free between V-GEMM and Wo cast (1MB used)

  cast_kernel<<<8192, 256, 0, stream>>>(x, xb);
  cast_kernel<<<16384, 256, 0, stream>>>(Wq, Wb);
  gemm_bt<0><<<512, 256, 0, stream>>>(xb, Wb, bq, Qb);
  cast_kernel<<<16384, 256, 0, stream>>>(Wk, Wb);
  gemm_bt<0><<<512, 256, 0, stream>>>(xb, Wb, bk, Kb);
  cast_kernel<<<16384, 256, 0, stream>>>(Wv, Wb);
  gemm_bt<0><<<512, 256, 0, stream>>>(xb, Wb, bv, Vb);
  rope_table<<<512, 256, 0, stream>>>(tab);
  rope_kernel<<<dim3(4096, 2), 256, 0, stream>>>(Qb, Kb, tab);
  transpose_v<<<dim3(32, 2, 32), 256, 0, stream>>>(Vb, Vt);
  attn_kernel<<<256, 512, 0, stream>>>(Qb, Kb, Vt, aO);
  cast_kernel<<<16384, 256, 0, stream>>>(Wo, Wb);
  gemm_bt<1><<<512, 256, 0, stream>>>(aO, Wb, bo, out);
}